// Round 9
// baseline (5323.233 us; speedup 1.0000x reference)
//
#include <hip/hip_runtime.h>

#define ALPHA 0.9f
#define THRESH 1.0f
#define BATCH 512
#define CIN 16
#define TSTEPS 2000
#define NRES 1024
#define NCLS 10

#define NGROUP 32       // 32 batch groups of 16 rows
#define BPG 8           // blocks per group, 128 neurons each

typedef int   v4i __attribute__((ext_vector_type(4)));
typedef float v4f __attribute__((ext_vector_type(4)));
typedef short v8s __attribute__((ext_vector_type(8)));

// ---- ws layout (bytes) ----
#define SLOTC_OFF  8192     // max|W_clf| bits
#define ROWMAX_OFF 9216     // per-row max|W_res[n][:]|, 1024 floats
// tagged masks, PRODUCER-MAJOR: 2 par x 32 g x 64 producer x 16 row x 4 B = 256 KB
// (wave publish = lanes 0..15 -> ONE contiguous 64B line at P*64)
#define MASK_OFF   16384
#define WQF_OFF    278528   // W_res int8, MFMA-fragment order: 1 MB
#define WCF_OFF    1327104  // W_clf int8 fragment tile: 16 KB
#define LDS_BYTES  (131072 + 16*1040 + 1024 + 8192)  // B slice + A + xA + redC

__global__ __launch_bounds__(256) void maxabs_kernel(const float* __restrict__ W,
                                                     int n, unsigned* __restrict__ slot) {
    unsigned m = 0u;
    for (int i = blockIdx.x * 256 + threadIdx.x; i < n; i += gridDim.x * 256)
        m = max(m, __float_as_uint(W[i]) & 0x7fffffffu);
#pragma unroll
    for (int off = 32; off >= 1; off >>= 1)
        m = max(m, (unsigned)__shfl_xor((int)m, off, 64));
    if ((threadIdx.x & 63) == 0) atomicMax(slot, m);
}

// per-row max|W_res[n][:]| — one wave per row, plain store (deterministic)
__global__ __launch_bounds__(256) void rowmax_kernel(const float* __restrict__ W,
                                                     float* __restrict__ rowmax) {
    const int row = blockIdx.x * 4 + ((int)threadIdx.x >> 6);
    const int lane = threadIdx.x & 63;
    float m = 0.f;
    for (int j = lane; j < NRES; j += 64) m = fmaxf(m, fabsf(W[row * NRES + j]));
#pragma unroll
    for (int off = 32; off >= 1; off >>= 1) m = fmaxf(m, __shfl_xor(m, off, 64));
    if (lane == 0) rowmax[row] = m;
}

// W_res -> signed-int8 (PER-ROW scale) in MFMA B-fragment order:
// dword o4: bl=o4>>15, wv=(o4>>12)&7, kt=(o4>>8)&15, L=(o4>>2)&63, i0=(o4&3)*4
// n = bl*128+wv*16+(L&15); k = kt*64+(L>>4)*16+i0..+3
__global__ __launch_bounds__(256) void quant_res(const float* __restrict__ W,
                                                 const float* __restrict__ rowmax,
                                                 unsigned* __restrict__ dst) {
    const int o4 = blockIdx.x * 256 + threadIdx.x;
    const int bl = o4 >> 15, wv = (o4 >> 12) & 7, kt = (o4 >> 8) & 15;
    const int L = (o4 >> 2) & 63, i0 = (o4 & 3) * 4;
    const int n = bl * 128 + wv * 16 + (L & 15);
    const int k = kt * 64 + (L >> 4) * 16 + i0;
    const float inv = 127.0f / rowmax[n];
    unsigned dw = 0;
#pragma unroll
    for (int j = 0; j < 4; ++j) {
        float q = rintf(W[n * NRES + k + j] * inv);
        q = fminf(fmaxf(q, -127.f), 127.f);
        dw |= ((unsigned)((int)q & 0xff)) << (8 * j);
    }
    dst[o4] = dw;
}

// W_clf -> int8 fragment tile (16 cols, cls>=10 zero): 4096 dwords
__global__ __launch_bounds__(256) void quant_clf(const float* __restrict__ W,
                                                 const unsigned* __restrict__ slot,
                                                 unsigned* __restrict__ dst) {
    const int o4 = blockIdx.x * 256 + threadIdx.x;
    const int kt = (o4 >> 8) & 15, L = (o4 >> 2) & 63, i0 = (o4 & 3) * 4;
    const int cls = L & 15;
    const int k = kt * 64 + (L >> 4) * 16 + i0;
    const float inv = 127.0f / __uint_as_float(*slot);
    unsigned dw = 0;
    if (cls < NCLS) {
#pragma unroll
        for (int j = 0; j < 4; ++j) {
            float q = rintf(W[cls * NRES + k + j] * inv);
            q = fminf(fmaxf(q, -127.f), 127.f);
            dw |= ((unsigned)((int)q & 0xff)) << (8 * j);
        }
    }
    dst[o4] = dw;
}

__device__ __forceinline__ unsigned short f2bf(float f) {
    unsigned u = __float_as_uint(f);
    return (unsigned short)((u + 0x7fffu + ((u >> 16) & 1u)) >> 16);
}

// 16 spike bits -> 16 int8 {0,1} bytes (carry-free nibble spread:
// x*0x00204081 places bits at 0/8/16/24; shifts never overlap for x<16)
__device__ __forceinline__ v4i expand16(unsigned m16) {
    unsigned w[4];
#pragma unroll
    for (int d = 0; d < 4; ++d)
        w[d] = (((m16 >> (4 * d)) & 15u) * 0x00204081u) & 0x01010101u;
    return *(v4i*)&w[0];
}

// ---------------------------------------------------------------------------
// 256 blocks x 512 threads (1/CU). Block = (group g, slot bl): 16 batch rows
// x 128 neurons, int8 W slice LDS-resident. Producer-major tagged-mask
// transport (verified 3.48 ms kernel). SINGLE structural change vs that
// kernel: the poll SPIN is moved to BEFORE S3 (right after publish), holding
// the fetched mask dwords in registers across the barrier; the LDS expand/
// A-write stays at the loop top (post-S3). This overlaps the publish store's
// coherence-point ACK (which S3's vmcnt(0) drain otherwise serializes) with
// the poll RTT — in R6 they were back-to-back. Deadlock-free: every producer
// publishes before entering its spin. x is register-prefetched one step ahead
// (its old latency cover, the loop-top poll, is gone). All LDS hazard
// orderings unchanged: A-writes post-S3, A-reads pre-publish.
// Numerics bit-identical (absmax must be exactly 32).
// ---------------------------------------------------------------------------
__global__ __launch_bounds__(512, 1) void reservoir_mfma(
    const float* __restrict__ x, const float* __restrict__ W_in,
    unsigned char* __restrict__ ws, float* __restrict__ out)
{
    // XCD co-location: 8 blocks of a group share q%8 (dispatch heuristic).
    const int q   = (int)blockIdx.x;
    const int g   = (q & 7) * 4 + ((q >> 3) & 3);
    const int bl  = q >> 5;
    const int tid = (int)threadIdx.x;
    const int L    = tid & 63;
    const int wv   = tid >> 6;     // 0..7
    const int col  = L & 15;       // MFMA n-col (neuron/cls)
    const int rowq = L >> 4;       // batch quad

    extern __shared__ char lds[];
    char* B_lds = lds;                                   // 131072 B
    char* A_lds = lds + 131072;                          // 16 x 1040 B
    unsigned short* xA = (unsigned short*)(lds + 131072 + 16 * 1040);  // 16x32 bf16
    char* redC = lds + 131072 + 16 * 1040 + 1024;        // 8 KB clf partials

    const float* rowmax = (const float*)(ws + ROWMAX_OFF);
    const float cscale = __uint_as_float(*(const unsigned*)(ws + SLOTC_OFF)) * (1.0f / 127.0f);
    unsigned char* maskbuf = ws + MASK_OFF;
    const unsigned char* wqf = ws + WQF_OFF;
    const unsigned char* wcf = ws + WCF_OFF;

    const int nn = bl * 128 + wv * 16 + col;             // my output neuron
    const float dscale = rowmax[nn] * (1.0f / 127.0f);
    const bool clfBlk = (bl == 0);

    // ---- load my 128 KB weight slice into LDS
    {
        const v4i* src = (const v4i*)(wqf + (size_t)bl * 131072);
        v4i* dst = (v4i*)B_lds;
        for (int i = tid; i < 8192; i += 512) dst[i] = src[i];
    }

    // ---- W_in hi/lo bf16 B-fragments
    v8s binf_h, binf_l;
#pragma unroll
    for (int i = 0; i < 8; ++i) {
        const int c = (rowq * 8 + i) & 15;
        const float w = W_in[nn * CIN + c];
        const unsigned short h = f2bf(w);
        const float wl = w - __uint_as_float((unsigned)h << 16);
        binf_h[i] = (short)h;
        binf_l[i] = (short)f2bf(wl);
    }

    // ---- classifier fragments preloaded to registers (block 0: wave wv owns kt=2wv,2wv+1)
    v4i bcf0 = {0,0,0,0}, bcf1 = {0,0,0,0};
    if (clfBlk) {
        bcf0 = *(const v4i*)(wcf + (2 * wv + 0) * 1024 + L * 16);
        bcf1 = *(const v4i*)(wcf + (2 * wv + 1) * 1024 + L * 16);
    }

    float v[4]  = {0.f, 0.f, 0.f, 0.f};
    int   accv[4] = {0, 0, 0, 0};
    float vc[4] = {0.f, 0.f, 0.f, 0.f};   // live on block0/wave0
    int   accc[4] = {0, 0, 0, 0};

    // mask poll (producer-major): thread tt polls producer P=tt>>3, rows 2k/2k+1
    const int pP = tid >> 3, pk = tid & 7;
    const unsigned long long* mybase0 = (const unsigned long long*)(maskbuf +
        (size_t)(0 * NGROUP + g) * 4096 + pP * 64 + pk * 8);
    const unsigned long long* mybase1 = (const unsigned long long*)(maskbuf +
        (size_t)(1 * NGROUP + g) * 4096 + pP * 64 + pk * 8);

    // x element (tid<256): register-prefetched one step ahead
    const int xb = (tid >> 4) & 15, xc = tid & 15;
    const size_t xoff = ((size_t)(g * 16 + xb) * CIN + xc) * TSTEPS;
    float xval = (tid < 256) ? x[xoff] : 0.f;

    unsigned plo = 0, phi = 0;   // mask dwords fetched by the pre-S3 spin

    __syncthreads();

    for (int t = 0; t < TSTEPS; ++t) {
        // ---- loop top (post-S3 of t-1): expand the masks fetched by the
        //      previous iteration's spin into A (LDS write — ordered by S3)
        if (t > 0) {
            *(v4i*)(A_lds + (2 * pk + 0) * 1040 + pP * 16) = expand16(plo & 0xffffu);
            *(v4i*)(A_lds + (2 * pk + 1) * 1040 + pP * 16) = expand16(phi & 0xffffu);
        }
        // ---- stage x_t hi/lo (xval prefetched last iteration)
        if (tid < 256) {
            const unsigned short h = f2bf(xval);
            const float lo2 = xval - __uint_as_float((unsigned)h << 16);
            xA[xb * 32 + xc] = h;
            xA[xb * 32 + 16 + xc] = f2bf(lo2);
        }
        __syncthreads();   // S2: A + xA ready

        // ---- prefetch next step's x under the MFMA phase
        float xnext = 0.f;
        if (tid < 256 && t + 1 < TSTEPS) xnext = x[xoff + (t + 1)];

        // ---- input projection: (xh+xl).(Wh+Wl), 2 chained bf16 MFMAs
        v4f Din;
        {
            const v8s xa = *(const v8s*)((const char*)xA + col * 64 + rowq * 16);
            v4f z = {0.f, 0.f, 0.f, 0.f};
            const v4f D1 = __builtin_amdgcn_mfma_f32_16x16x32_bf16(xa, binf_h, z, 0, 0, 0);
            Din = __builtin_amdgcn_mfma_f32_16x16x32_bf16(xa, binf_l, D1, 0, 0, 0);
        }

        // ---- recurrent: 16 x mfma_i32_16x16x64_i8, 2 independent chains (exact)
        v4i Drec = {0, 0, 0, 0};
        if (t > 0) {
            const char* Bb = B_lds + wv * 16384;
            const char* Ab = A_lds + col * 1040 + rowq * 16;
            v4i Dr0 = {0,0,0,0}, Dr1 = {0,0,0,0};
#pragma unroll 4
            for (int kt = 0; kt < 16; kt += 2) {
                const v4i a0 = *(const v4i*)(Ab + kt * 64);
                const v4i b0 = *(const v4i*)(Bb + kt * 1024 + L * 16);
                const v4i a1 = *(const v4i*)(Ab + (kt + 1) * 64);
                const v4i b1 = *(const v4i*)(Bb + (kt + 1) * 1024 + L * 16);
                Dr0 = __builtin_amdgcn_mfma_i32_16x16x64_i8(a0, b0, Dr0, 0, 0, 0);
                Dr1 = __builtin_amdgcn_mfma_i32_16x16x64_i8(a1, b1, Dr1, 0, 0, 0);
            }
#pragma unroll
            for (int r = 0; r < 4; ++r) Drec[r] = Dr0[r] + Dr1[r];
        }

        // ---- LIF + spikes + ballots
        unsigned long long bal0, bal1, bal2, bal3;
        {
            float vn; int s;
            vn = ALPHA * v[0] + Din[0] + dscale * (float)Drec[0];
            s = (vn >= THRESH); accv[0] += s; v[0] = s ? 0.f : vn; bal0 = __ballot(s);
            vn = ALPHA * v[1] + Din[1] + dscale * (float)Drec[1];
            s = (vn >= THRESH); accv[1] += s; v[1] = s ? 0.f : vn; bal1 = __ballot(s);
            vn = ALPHA * v[2] + Din[2] + dscale * (float)Drec[2];
            s = (vn >= THRESH); accv[2] += s; v[2] = s ? 0.f : vn; bal2 = __ballot(s);
            vn = ALPHA * v[3] + Din[3] + dscale * (float)Drec[3];
            s = (vn >= THRESH); accv[3] += s; v[3] = s ? 0.f : vn; bal3 = __ballot(s);
        }

        // ---- publish tagged masks (tag = t+1): lanes 0..15 write ONE
        //      contiguous 64B line at producer slot P=bl*8+wv
        {
            const int p = t & 1;
            if (L < 16) {
                const int b = L;
                const unsigned long long bb = (b & 2) ? ((b & 1) ? bal3 : bal2)
                                                      : ((b & 1) ? bal1 : bal0);
                const unsigned fld = (unsigned)((bb >> ((b >> 2) * 16)) & 0xFFFFu);
                unsigned* mp = (unsigned*)(maskbuf +
                    (size_t)(p * NGROUP + g) * 4096 + (bl * 8 + wv) * 64 + b * 4);
                __hip_atomic_store(mp, ((unsigned)(t + 1) << 16) | fld,
                                   __ATOMIC_RELAXED, __HIP_MEMORY_SCOPE_AGENT);
            }
        }

        // ---- classifier partials (block 0, spread: wave wv does kt=2wv,2wv+1)
        if (clfBlk && t > 0) {
            const char* Ab = A_lds + col * 1040 + rowq * 16;
            v4i Dc = {0, 0, 0, 0};
            const v4i a0 = *(const v4i*)(Ab + (2 * wv + 0) * 64);
            const v4i a1 = *(const v4i*)(Ab + (2 * wv + 1) * 64);
            Dc = __builtin_amdgcn_mfma_i32_16x16x64_i8(a0, bcf0, Dc, 0, 0, 0);
            Dc = __builtin_amdgcn_mfma_i32_16x16x64_i8(a1, bcf1, Dc, 0, 0, 0);
            *(v4i*)(redC + wv * 1024 + L * 16) = Dc;
        }

        // ---- pre-S3 SPIN for tag t+1 (this step's publishes, parity t&1).
        //      Overlaps the publish ACK that S3's vmcnt(0) drain would
        //      otherwise serialize before the poll. Registers only.
        {
            const unsigned long long* mp = (t & 1) ? mybase1 : mybase0;
            const unsigned want = (unsigned)(t + 1);
            for (;;) {
                const unsigned long long u =
                    __hip_atomic_load(mp, __ATOMIC_RELAXED, __HIP_MEMORY_SCOPE_AGENT);
                plo = (unsigned)u; phi = (unsigned)(u >> 32);
                if (((plo >> 16) == want) & ((phi >> 16) == want)) break;
                __builtin_amdgcn_s_sleep(1);
            }
        }
        __syncthreads();   // S3: A/xA consumed; redC ready (ack already done)

        // ---- classifier reduce + LIF (block 0, wave 0; reads redC after S3)
        if (clfBlk && wv == 0 && t > 0) {
            v4i c0 = *(const v4i*)(redC + 0 * 1024 + L * 16);
#pragma unroll
            for (int jj = 1; jj < 8; ++jj) {
                const v4i cj = *(const v4i*)(redC + jj * 1024 + L * 16);
#pragma unroll
                for (int r = 0; r < 4; ++r) c0[r] += cj[r];
            }
#pragma unroll
            for (int r = 0; r < 4; ++r) {
                const float vcn = ALPHA * vc[r] + cscale * (float)c0[r];
                const int sc = (vcn >= THRESH);
                accc[r] += sc;
                vc[r] = sc ? 0.f : vcn;
            }
        }
        xval = xnext;
        // no end-of-loop barrier: S3 separates this step's A/xA reads from the
        // next step's A/xA writes at the loop top.
    }

    // ---- epilogue: classifier flush with s_{T-1}. The loop's final spin
    //      (t=1999, parity 1, want 2000) left the tagged masks in plo/phi.
    if (clfBlk) {
        *(v4i*)(A_lds + (2 * pk + 0) * 1040 + pP * 16) = expand16(plo & 0xffffu);
        *(v4i*)(A_lds + (2 * pk + 1) * 1040 + pP * 16) = expand16(phi & 0xffffu);
        __syncthreads();
        {
            const char* Ab = A_lds + col * 1040 + rowq * 16;
            v4i Dc = {0, 0, 0, 0};
            const v4i a0 = *(const v4i*)(Ab + (2 * wv + 0) * 64);
            const v4i a1 = *(const v4i*)(Ab + (2 * wv + 1) * 64);
            Dc = __builtin_amdgcn_mfma_i32_16x16x64_i8(a0, bcf0, Dc, 0, 0, 0);
            Dc = __builtin_amdgcn_mfma_i32_16x16x64_i8(a1, bcf1, Dc, 0, 0, 0);
            *(v4i*)(redC + wv * 1024 + L * 16) = Dc;
        }
        __syncthreads();
        if (wv == 0 && col < NCLS) {
            v4i c0 = *(const v4i*)(redC + 0 * 1024 + L * 16);
#pragma unroll
            for (int jj = 1; jj < 8; ++jj) {
                const v4i cj = *(const v4i*)(redC + jj * 1024 + L * 16);
#pragma unroll
                for (int r = 0; r < 4; ++r) c0[r] += cj[r];
            }
#pragma unroll
            for (int r = 0; r < 4; ++r) {
                const float vcn = ALPHA * vc[r] + cscale * (float)c0[r];
                const int sc = (vcn >= THRESH);
                out[(size_t)(g * 16 + rowq * 4 + r) * NCLS + col] = (float)(accc[r] + sc);
            }
        }
    }
    {
#pragma unroll
        for (int r = 0; r < 4; ++r) {
            const int bglob = g * 16 + rowq * 4 + r;
            out[BATCH * NCLS + (size_t)bglob * NRES + nn] = (float)accv[r];
        }
    }
}

extern "C" void kernel_launch(void* const* d_in, const int* in_sizes, int n_in,
                              void* d_out, int out_size, void* d_ws, size_t ws_size,
                              hipStream_t stream) {
    (void)in_sizes; (void)n_in; (void)out_size; (void)ws_size;
    const float* x     = (const float*)d_in[0];
    const float* W_in  = (const float*)d_in[1];
    const float* W_res = (const float*)d_in[2];
    const float* W_clf = (const float*)d_in[3];
    float* out = (float*)d_out;
    unsigned char* ws = (unsigned char*)d_ws;

    // zero: scale slots + rowmax + ENTIRE tagged-mask region (tags 0 never match)
    hipMemsetAsync(ws, 0, MASK_OFF + 262144, stream);
    rowmax_kernel<<<256, 256, 0, stream>>>(W_res, (float*)(ws + ROWMAX_OFF));
    maxabs_kernel<<<16, 256, 0, stream>>>(W_clf, NCLS * NRES, (unsigned*)(ws + SLOTC_OFF));
    quant_res<<<1024, 256, 0, stream>>>(W_res, (const float*)(ws + ROWMAX_OFF),
                                        (unsigned*)(ws + WQF_OFF));
    quant_clf<<<16, 256, 0, stream>>>(W_clf, (const unsigned*)(ws + SLOTC_OFF),
                                      (unsigned*)(ws + WCF_OFF));
    reservoir_mfma<<<NGROUP * BPG, 512, LDS_BYTES, stream>>>(x, W_in, ws, out);
}

// Round 11
// 3787.933 us; speedup vs baseline: 1.4053x; 1.4053x over previous
//
#include <hip/hip_runtime.h>

#define ALPHA 0.9f
#define THRESH 1.0f
#define BATCH 512
#define CIN 16
#define TSTEPS 2000
#define NRES 1024
#define NCLS 10

#define NGROUP 32       // 32 batch groups of 16 rows
#define BPG 8           // blocks per group, 128 neurons each

typedef int   v4i __attribute__((ext_vector_type(4)));
typedef float v4f __attribute__((ext_vector_type(4)));
typedef short v8s __attribute__((ext_vector_type(8)));

// ---- ws layout (bytes) ----
#define CLAIM_OFF  256      // 256 x u32 slot-claim flags (CAS), ends 1280
#define SLOTC_OFF  8192     // max|W_clf| bits
#define ROWMAX_OFF 9216     // per-row max|W_res[n][:]|, 1024 floats
// tagged masks, PRODUCER-MAJOR (2 par x 32 g x 64 producer x 16 row x 4 B):
#define MASK_OFF   16384    // L buffer: plain stores (dirty in shared same-XCD L2)
#define MASKG_OFF  278528   // G buffer: agent-scope write-through backstop
#define WQF_OFF    540672   // W_res int8, MFMA-fragment order: 1 MB
#define WCF_OFF    1589248  // W_clf int8 fragment tile: 16 KB
// LDS: B slice + A + xA + redC + assignment-broadcast slot
#define LDS_BYTES  (131072 + 16*1040 + 1024 + 8192 + 16)

__global__ __launch_bounds__(256) void maxabs_kernel(const float* __restrict__ W,
                                                     int n, unsigned* __restrict__ slot) {
    unsigned m = 0u;
    for (int i = blockIdx.x * 256 + threadIdx.x; i < n; i += gridDim.x * 256)
        m = max(m, __float_as_uint(W[i]) & 0x7fffffffu);
#pragma unroll
    for (int off = 32; off >= 1; off >>= 1)
        m = max(m, (unsigned)__shfl_xor((int)m, off, 64));
    if ((threadIdx.x & 63) == 0) atomicMax(slot, m);
}

// per-row max|W_res[n][:]| — one wave per row, plain store (deterministic)
__global__ __launch_bounds__(256) void rowmax_kernel(const float* __restrict__ W,
                                                     float* __restrict__ rowmax) {
    const int row = blockIdx.x * 4 + ((int)threadIdx.x >> 6);
    const int lane = threadIdx.x & 63;
    float m = 0.f;
    for (int j = lane; j < NRES; j += 64) m = fmaxf(m, fabsf(W[row * NRES + j]));
#pragma unroll
    for (int off = 32; off >= 1; off >>= 1) m = fmaxf(m, __shfl_xor(m, off, 64));
    if (lane == 0) rowmax[row] = m;
}

// W_res -> signed-int8 (PER-ROW scale) in MFMA B-fragment order:
// dword o4: bl=o4>>15, wv=(o4>>12)&7, kt=(o4>>8)&15, L=(o4>>2)&63, i0=(o4&3)*4
// n = bl*128+wv*16+(L&15); k = kt*64+(L>>4)*16+i0..+3
__global__ __launch_bounds__(256) void quant_res(const float* __restrict__ W,
                                                 const float* __restrict__ rowmax,
                                                 unsigned* __restrict__ dst) {
    const int o4 = blockIdx.x * 256 + threadIdx.x;
    const int bl = o4 >> 15, wv = (o4 >> 12) & 7, kt = (o4 >> 8) & 15;
    const int L = (o4 >> 2) & 63, i0 = (o4 & 3) * 4;
    const int n = bl * 128 + wv * 16 + (L & 15);
    const int k = kt * 64 + (L >> 4) * 16 + i0;
    const float inv = 127.0f / rowmax[n];
    unsigned dw = 0;
#pragma unroll
    for (int j = 0; j < 4; ++j) {
        float q = rintf(W[n * NRES + k + j] * inv);
        q = fminf(fmaxf(q, -127.f), 127.f);
        dw |= ((unsigned)((int)q & 0xff)) << (8 * j);
    }
    dst[o4] = dw;
}

// W_clf -> int8 fragment tile (16 cols, cls>=10 zero): 4096 dwords
__global__ __launch_bounds__(256) void quant_clf(const float* __restrict__ W,
                                                 const unsigned* __restrict__ slot,
                                                 unsigned* __restrict__ dst) {
    const int o4 = blockIdx.x * 256 + threadIdx.x;
    const int kt = (o4 >> 8) & 15, L = (o4 >> 2) & 63, i0 = (o4 & 3) * 4;
    const int cls = L & 15;
    const int k = kt * 64 + (L >> 4) * 16 + i0;
    const float inv = 127.0f / __uint_as_float(*slot);
    unsigned dw = 0;
    if (cls < NCLS) {
#pragma unroll
        for (int j = 0; j < 4; ++j) {
            float q = rintf(W[cls * NRES + k + j] * inv);
            q = fminf(fmaxf(q, -127.f), 127.f);
            dw |= ((unsigned)((int)q & 0xff)) << (8 * j);
        }
    }
    dst[o4] = dw;
}

__device__ __forceinline__ unsigned short f2bf(float f) {
    unsigned u = __float_as_uint(f);
    return (unsigned short)((u + 0x7fffu + ((u >> 16) & 1u)) >> 16);
}

// 16 spike bits -> 16 int8 {0,1} bytes (carry-free nibble spread:
// x*0x00204081 places bits at 0/8/16/24; shifts never overlap for x<16)
__device__ __forceinline__ v4i expand16(unsigned m16) {
    unsigned w[4];
#pragma unroll
    for (int d = 0; d < 4; ++d)
        w[d] = (((m16 >> (4 * d)) & 15u) * 0x00204081u) & 0x01010101u;
    return *(v4i*)&w[0];
}

// Hybrid tagged-mask poll. Fast path: sc0 (L1-bypass) load of the plain-store
// L buffer — the producer is RUNTIME-VERIFIED same-XCD, so its dirty line
// lives in the SHARED local L2 (~300 cy RTT, no fabric crossing). Backstop:
// agent-scope load of the write-through G buffer every 4th try (correct under
// any placement anomaly). Tags self-validate; a stale L2 copy can only carry
// an OLDER tag (monotone), never a false match. s_sleep cadence retained
// (R7/R9: sleepless spins congest the coherence point producers commit via).
__device__ __forceinline__ unsigned long long hybrid_poll2(
        const unsigned long long* mpL, const unsigned long long* mpG, unsigned want) {
    int tries = 0;
    for (;;) {
        unsigned long long u;
        if ((tries & 3) != 3) {
            asm volatile("global_load_dwordx2 %0, %1, off sc0\n\ts_waitcnt vmcnt(0)"
                         : "=v"(u) : "v"(mpL) : "memory");
        } else {
            u = __hip_atomic_load(mpG, __ATOMIC_RELAXED, __HIP_MEMORY_SCOPE_AGENT);
        }
        const unsigned lo = (unsigned)u, hi = (unsigned)(u >> 32);
        if (((lo >> 16) == want) & ((hi >> 16) == want)) return u;
        if (tries >= 2) __builtin_amdgcn_s_sleep(1);
        ++tries;
    }
}

// ---------------------------------------------------------------------------
// 256 blocks x 512 threads (LDS caps at 1 block/CU -> all 256 CUs host one
// block, fully co-resident). Structure identical to the VERIFIED 3.48 ms
// producer-major kernel EXCEPT group formation + transport:
//  (1) RUNTIME XCD DISCOVERY, WAIT-FREE: thread 0 reads HW_REG_XCC_ID
//      [HW-verified gfx950] and atomicCAS-claims a slot in its own XCD's
//      32-slot range (32 CUs/XCD x 1 block/CU -> always succeeds; full-range
//      CAS sweep as anomaly fallback). No cross-block waiting anywhere
//      outside the mask protocol — hang-proof by construction (R10 lesson).
//      Groups = 8 blocks PROVEN to share an XCD (4 groups/XCD).
//  (2) dual-publish: plain store to maskL (dirty in the SHARED same-XCD L2,
//      fast path) + agent-scope store to maskG (memory-side backstop).
//  (3) hybrid poll: sc0 loads of maskL (local L2 hits, no fabric traffic),
//      agent backstop interleaved.
// Numerics bit-identical (absmax must be exactly 32).
// ---------------------------------------------------------------------------
__global__ __launch_bounds__(512, 1) void reservoir_mfma(
    const float* __restrict__ x, const float* __restrict__ W_in,
    unsigned char* __restrict__ ws, float* __restrict__ out)
{
    const int tid = (int)threadIdx.x;
    const int L    = tid & 63;
    const int wv   = tid >> 6;     // 0..7
    const int col  = L & 15;       // MFMA n-col (neuron/cls)
    const int rowq = L >> 4;       // batch quad

    extern __shared__ char lds[];
    char* B_lds = lds;                                   // 131072 B
    char* A_lds = lds + 131072;                          // 16 x 1040 B
    unsigned short* xA = (unsigned short*)(lds + 131072 + 16 * 1040);  // 16x32 bf16
    char* redC = lds + 131072 + 16 * 1040 + 1024;        // 8 KB clf partials
    volatile int* bcast = (volatile int*)(lds + 131072 + 16 * 1040 + 1024 + 8192);

    // ---- wait-free XCD discovery + slot claim (thread 0) ----
    if (tid == 0) {
        unsigned xcd;
        asm volatile("s_getreg_b32 %0, hwreg(HW_REG_XCC_ID)" : "=s"(xcd));
        xcd &= 7u;
        unsigned* claimed = (unsigned*)(ws + CLAIM_OFF);
        int id = -1;
        // prefer my own XCD's 32 slots (always succeeds: 32 CUs/XCD, 1 blk/CU)
        for (int i = 0; i < 32 && id < 0; ++i) {
            const int cand = (int)(xcd * 32u) + i;
            if (atomicCAS(&claimed[cand], 0u, 1u) == 0u) id = cand;
        }
        // anomaly fallback: claim any free slot (dead code when XCC_ID sane)
        for (int i = 0; i < 256 && id < 0; ++i)
            if (atomicCAS(&claimed[i], 0u, 1u) == 0u) id = i;
        *bcast = id;
    }
    __syncthreads();
    const int gbl = *bcast;
    const int g  = gbl >> 3;       // group: 8 same-XCD blocks (4 groups/XCD)
    const int bl = gbl & 7;        // slot within group (128 neurons)

    const float* rowmax = (const float*)(ws + ROWMAX_OFF);
    const float cscale = __uint_as_float(*(const unsigned*)(ws + SLOTC_OFF)) * (1.0f / 127.0f);
    unsigned char* maskL = ws + MASK_OFF;
    unsigned char* maskG = ws + MASKG_OFF;
    const unsigned char* wqf = ws + WQF_OFF;
    const unsigned char* wcf = ws + WCF_OFF;

    const int nn = bl * 128 + wv * 16 + col;             // my output neuron
    const float dscale = rowmax[nn] * (1.0f / 127.0f);
    const bool clfBlk = (bl == 0);

    // ---- load my 128 KB weight slice into LDS
    {
        const v4i* src = (const v4i*)(wqf + (size_t)bl * 131072);
        v4i* dst = (v4i*)B_lds;
        for (int i = tid; i < 8192; i += 512) dst[i] = src[i];
    }

    // ---- W_in hi/lo bf16 B-fragments
    v8s binf_h, binf_l;
#pragma unroll
    for (int i = 0; i < 8; ++i) {
        const int c = (rowq * 8 + i) & 15;
        const float w = W_in[nn * CIN + c];
        const unsigned short h = f2bf(w);
        const float wl = w - __uint_as_float((unsigned)h << 16);
        binf_h[i] = (short)h;
        binf_l[i] = (short)f2bf(wl);
    }

    // ---- classifier fragments preloaded to registers (block 0: wave wv owns kt=2wv,2wv+1)
    v4i bcf0 = {0,0,0,0}, bcf1 = {0,0,0,0};
    if (clfBlk) {
        bcf0 = *(const v4i*)(wcf + (2 * wv + 0) * 1024 + L * 16);
        bcf1 = *(const v4i*)(wcf + (2 * wv + 1) * 1024 + L * 16);
    }

    float v[4]  = {0.f, 0.f, 0.f, 0.f};
    int   accv[4] = {0, 0, 0, 0};
    float vc[4] = {0.f, 0.f, 0.f, 0.f};   // live on block0/wave0
    int   accc[4] = {0, 0, 0, 0};

    // mask poll (producer-major): thread tt polls producer P=tt>>3, rows 2k/2k+1
    const int pP = tid >> 3, pk = tid & 7;
    const size_t moff0 = (size_t)(0 * NGROUP + g) * 4096 + pP * 64 + pk * 8;
    const size_t moff1 = (size_t)(1 * NGROUP + g) * 4096 + pP * 64 + pk * 8;
    const unsigned long long* mL0 = (const unsigned long long*)(maskL + moff0);
    const unsigned long long* mL1 = (const unsigned long long*)(maskL + moff1);
    const unsigned long long* mG0 = (const unsigned long long*)(maskG + moff0);
    const unsigned long long* mG1 = (const unsigned long long*)(maskG + moff1);

    __syncthreads();

    for (int t = 0; t < TSTEPS; ++t) {
        // x_t load issued before the poll
        float xval = 0.f;
        if (tid < 256) {
            const int b = tid >> 4, c = tid & 15;
            xval = x[((size_t)(g * 16 + b) * CIN + c) * TSTEPS + t];
        }

        if (t > 0) {
            // ---- hybrid-poll tagged masks of step t-1 (parity (t-1)&1)
            const int pp = (t - 1) & 1;
            const unsigned long long u =
                hybrid_poll2(pp ? mL1 : mL0, pp ? mG1 : mG0, (unsigned)t);
            const unsigned lo = (unsigned)u, hi = (unsigned)(u >> 32);
            // rows 2k (lo) and 2k+1 (hi) of producer P -> A[row][16P..16P+15]
            *(v4i*)(A_lds + (2 * pk + 0) * 1040 + pP * 16) = expand16(lo & 0xffffu);
            *(v4i*)(A_lds + (2 * pk + 1) * 1040 + pP * 16) = expand16(hi & 0xffffu);
        }
        // ---- stage x_t hi/lo
        if (tid < 256) {
            const int b = tid >> 4, c = tid & 15;
            const unsigned short h = f2bf(xval);
            const float lo2 = xval - __uint_as_float((unsigned)h << 16);
            xA[b * 32 + c] = h;
            xA[b * 32 + 16 + c] = f2bf(lo2);
        }
        __syncthreads();   // S2: A + xA ready

        // ---- input projection: (xh+xl).(Wh+Wl), 2 chained bf16 MFMAs
        v4f Din;
        {
            const v8s xa = *(const v8s*)((const char*)xA + col * 64 + rowq * 16);
            v4f z = {0.f, 0.f, 0.f, 0.f};
            const v4f D1 = __builtin_amdgcn_mfma_f32_16x16x32_bf16(xa, binf_h, z, 0, 0, 0);
            Din = __builtin_amdgcn_mfma_f32_16x16x32_bf16(xa, binf_l, D1, 0, 0, 0);
        }

        // ---- recurrent: 16 x mfma_i32_16x16x64_i8, 2 independent chains (exact)
        v4i Drec = {0, 0, 0, 0};
        if (t > 0) {
            const char* Bb = B_lds + wv * 16384;
            const char* Ab = A_lds + col * 1040 + rowq * 16;
            v4i Dr0 = {0,0,0,0}, Dr1 = {0,0,0,0};
#pragma unroll 4
            for (int kt = 0; kt < 16; kt += 2) {
                const v4i a0 = *(const v4i*)(Ab + kt * 64);
                const v4i b0 = *(const v4i*)(Bb + kt * 1024 + L * 16);
                const v4i a1 = *(const v4i*)(Ab + (kt + 1) * 64);
                const v4i b1 = *(const v4i*)(Bb + (kt + 1) * 1024 + L * 16);
                Dr0 = __builtin_amdgcn_mfma_i32_16x16x64_i8(a0, b0, Dr0, 0, 0, 0);
                Dr1 = __builtin_amdgcn_mfma_i32_16x16x64_i8(a1, b1, Dr1, 0, 0, 0);
            }
#pragma unroll
            for (int r = 0; r < 4; ++r) Drec[r] = Dr0[r] + Dr1[r];
        }

        // ---- LIF + spikes + ballots
        unsigned long long bal0, bal1, bal2, bal3;
        {
            float vn; int s;
            vn = ALPHA * v[0] + Din[0] + dscale * (float)Drec[0];
            s = (vn >= THRESH); accv[0] += s; v[0] = s ? 0.f : vn; bal0 = __ballot(s);
            vn = ALPHA * v[1] + Din[1] + dscale * (float)Drec[1];
            s = (vn >= THRESH); accv[1] += s; v[1] = s ? 0.f : vn; bal1 = __ballot(s);
            vn = ALPHA * v[2] + Din[2] + dscale * (float)Drec[2];
            s = (vn >= THRESH); accv[2] += s; v[2] = s ? 0.f : vn; bal2 = __ballot(s);
            vn = ALPHA * v[3] + Din[3] + dscale * (float)Drec[3];
            s = (vn >= THRESH); accv[3] += s; v[3] = s ? 0.f : vn; bal3 = __ballot(s);
        }

        // ---- dual-publish tagged masks (tag = t+1): lanes 0..15 write ONE
        //      contiguous 64B line at producer slot P=bl*8+wv
        {
            const int p = t & 1;
            if (L < 16) {
                const int b = L;
                const unsigned long long bb = (b & 2) ? ((b & 1) ? bal3 : bal2)
                                                      : ((b & 1) ? bal1 : bal0);
                const unsigned fld = (unsigned)((bb >> ((b >> 2) * 16)) & 0xFFFFu);
                const unsigned val = ((unsigned)(t + 1) << 16) | fld;
                const size_t off = (size_t)(p * NGROUP + g) * 4096
                                 + (bl * 8 + wv) * 64 + b * 4;
                unsigned* mpL = (unsigned*)(maskL + off);
                unsigned* mpG = (unsigned*)(maskG + off);
                // fast path: plain store -> dirty in the SHARED same-XCD L2
                asm volatile("global_store_dword %0, %1, off"
                             :: "v"(mpL), "v"(val) : "memory");
                // backstop: agent-scope write-through (any placement)
                __hip_atomic_store(mpG, val, __ATOMIC_RELAXED, __HIP_MEMORY_SCOPE_AGENT);
            }
        }

        // ---- classifier partials (block 0, spread: wave wv does kt=2wv,2wv+1)
        if (clfBlk && t > 0) {
            const char* Ab = A_lds + col * 1040 + rowq * 16;
            v4i Dc = {0, 0, 0, 0};
            const v4i a0 = *(const v4i*)(Ab + (2 * wv + 0) * 64);
            const v4i a1 = *(const v4i*)(Ab + (2 * wv + 1) * 64);
            Dc = __builtin_amdgcn_mfma_i32_16x16x64_i8(a0, bcf0, Dc, 0, 0, 0);
            Dc = __builtin_amdgcn_mfma_i32_16x16x64_i8(a1, bcf1, Dc, 0, 0, 0);
            *(v4i*)(redC + wv * 1024 + L * 16) = Dc;
        }
        __syncthreads();   // S3: A consumed; redC ready

        // ---- classifier reduce + LIF (block 0, wave 0; reads redC after S3)
        if (clfBlk && wv == 0 && t > 0) {
            v4i c0 = *(const v4i*)(redC + 0 * 1024 + L * 16);
#pragma unroll
            for (int jj = 1; jj < 8; ++jj) {
                const v4i cj = *(const v4i*)(redC + jj * 1024 + L * 16);
#pragma unroll
                for (int r = 0; r < 4; ++r) c0[r] += cj[r];
            }
#pragma unroll
            for (int r = 0; r < 4; ++r) {
                const float vcn = ALPHA * vc[r] + cscale * (float)c0[r];
                const int sc = (vcn >= THRESH);
                accc[r] += sc;
                vc[r] = sc ? 0.f : vcn;
            }
        }
        // no end-of-loop barrier: S3 separates this step's A/xA reads from the
        // next step's poll-gated A/xA writes.
    }

    // ---- epilogue: classifier flush with s_{T-1} (parity 1, tag TSTEPS)
    if (clfBlk) {
        {
            const unsigned long long u = hybrid_poll2(mL1, mG1, (unsigned)TSTEPS);
            const unsigned lo = (unsigned)u, hi = (unsigned)(u >> 32);
            *(v4i*)(A_lds + (2 * pk + 0) * 1040 + pP * 16) = expand16(lo & 0xffffu);
            *(v4i*)(A_lds + (2 * pk + 1) * 1040 + pP * 16) = expand16(hi & 0xffffu);
        }
        __syncthreads();
        {
            const char* Ab = A_lds + col * 1040 + rowq * 16;
            v4i Dc = {0, 0, 0, 0};
            const v4i a0 = *(const v4i*)(Ab + (2 * wv + 0) * 64);
            const v4i a1 = *(const v4i*)(Ab + (2 * wv + 1) * 64);
            Dc = __builtin_amdgcn_mfma_i32_16x16x64_i8(a0, bcf0, Dc, 0, 0, 0);
            Dc = __builtin_amdgcn_mfma_i32_16x16x64_i8(a1, bcf1, Dc, 0, 0, 0);
            *(v4i*)(redC + wv * 1024 + L * 16) = Dc;
        }
        __syncthreads();
        if (wv == 0 && col < NCLS) {
            v4i c0 = *(const v4i*)(redC + 0 * 1024 + L * 16);
#pragma unroll
            for (int jj = 1; jj < 8; ++jj) {
                const v4i cj = *(const v4i*)(redC + jj * 1024 + L * 16);
#pragma unroll
                for (int r = 0; r < 4; ++r) c0[r] += cj[r];
            }
#pragma unroll
            for (int r = 0; r < 4; ++r) {
                const float vcn = ALPHA * vc[r] + cscale * (float)c0[r];
                const int sc = (vcn >= THRESH);
                out[(size_t)(g * 16 + rowq * 4 + r) * NCLS + col] = (float)(accc[r] + sc);
            }
        }
    }
    {
#pragma unroll
        for (int r = 0; r < 4; ++r) {
            const int bglob = g * 16 + rowq * 4 + r;
            out[BATCH * NCLS + (size_t)bglob * NRES + nn] = (float)accv[r];
        }
    }
}

extern "C" void kernel_launch(void* const* d_in, const int* in_sizes, int n_in,
                              void* d_out, int out_size, void* d_ws, size_t ws_size,
                              hipStream_t stream) {
    (void)in_sizes; (void)n_in; (void)out_size; (void)ws_size;
    const float* x     = (const float*)d_in[0];
    const float* W_in  = (const float*)d_in[1];
    const float* W_res = (const float*)d_in[2];
    const float* W_clf = (const float*)d_in[3];
    float* out = (float*)d_out;
    unsigned char* ws = (unsigned char*)d_ws;

    // zero: claim flags + scale slots + rowmax + BOTH mask regions
    hipMemsetAsync(ws, 0, MASK_OFF + 2 * 262144, stream);
    rowmax_kernel<<<256, 256, 0, stream>>>(W_res, (float*)(ws + ROWMAX_OFF));
    maxabs_kernel<<<16, 256, 0, stream>>>(W_clf, NCLS * NRES, (unsigned*)(ws + SLOTC_OFF));
    quant_res<<<1024, 256, 0, stream>>>(W_res, (const float*)(ws + ROWMAX_OFF),
                                        (unsigned*)(ws + WQF_OFF));
    quant_clf<<<16, 256, 0, stream>>>(W_clf, (const unsigned*)(ws + SLOTC_OFF),
                                      (unsigned*)(ws + WCF_OFF));
    reservoir_mfma<<<NGROUP * BPG, 512, LDS_BYTES, stream>>>(x, W_in, ws, out);
}

// Round 12
// 3481.758 us; speedup vs baseline: 1.5289x; 1.0879x over previous
//
#include <hip/hip_runtime.h>

#define ALPHA 0.9f
#define THRESH 1.0f
#define BATCH 512
#define CIN 16
#define TSTEPS 2000
#define NRES 1024
#define NCLS 10

#define NGROUP 32       // 32 batch groups of 16 rows
#define BPG 8           // blocks per group, 128 neurons each

typedef int   v4i __attribute__((ext_vector_type(4)));
typedef float v4f __attribute__((ext_vector_type(4)));
typedef short v8s __attribute__((ext_vector_type(8)));

// ---- ws layout (bytes) ----
#define SLOTC_OFF  8192     // max|W_clf| bits
#define ROWMAX_OFF 9216     // per-row max|W_res[n][:]|, 1024 floats
// tagged masks, PRODUCER-MAJOR: 2 par x 32 g x 64 producer x 16 row x 4 B = 256 KB
// (wave publish = lanes 0..15 -> ONE contiguous 64B line at P*64)
#define MASK_OFF   16384
#define WQF_OFF    278528   // W_res int8, MFMA-fragment order: 1 MB
#define WCF_OFF    1327104  // W_clf int8 fragment tile: 16 KB
#define LDS_BYTES  (131072 + 16*1040 + 1024 + 8192)  // B slice + A + xA + redC

__global__ __launch_bounds__(256) void maxabs_kernel(const float* __restrict__ W,
                                                     int n, unsigned* __restrict__ slot) {
    unsigned m = 0u;
    for (int i = blockIdx.x * 256 + threadIdx.x; i < n; i += gridDim.x * 256)
        m = max(m, __float_as_uint(W[i]) & 0x7fffffffu);
#pragma unroll
    for (int off = 32; off >= 1; off >>= 1)
        m = max(m, (unsigned)__shfl_xor((int)m, off, 64));
    if ((threadIdx.x & 63) == 0) atomicMax(slot, m);
}

// per-row max|W_res[n][:]| — one wave per row, plain store (deterministic)
__global__ __launch_bounds__(256) void rowmax_kernel(const float* __restrict__ W,
                                                     float* __restrict__ rowmax) {
    const int row = blockIdx.x * 4 + ((int)threadIdx.x >> 6);
    const int lane = threadIdx.x & 63;
    float m = 0.f;
    for (int j = lane; j < NRES; j += 64) m = fmaxf(m, fabsf(W[row * NRES + j]));
#pragma unroll
    for (int off = 32; off >= 1; off >>= 1) m = fmaxf(m, __shfl_xor(m, off, 64));
    if (lane == 0) rowmax[row] = m;
}

// W_res -> signed-int8 (PER-ROW scale) in MFMA B-fragment order:
// dword o4: bl=o4>>15, wv=(o4>>12)&7, kt=(o4>>8)&15, L=(o4>>2)&63, i0=(o4&3)*4
// n = bl*128+wv*16+(L&15); k = kt*64+(L>>4)*16+i0..+3
__global__ __launch_bounds__(256) void quant_res(const float* __restrict__ W,
                                                 const float* __restrict__ rowmax,
                                                 unsigned* __restrict__ dst) {
    const int o4 = blockIdx.x * 256 + threadIdx.x;
    const int bl = o4 >> 15, wv = (o4 >> 12) & 7, kt = (o4 >> 8) & 15;
    const int L = (o4 >> 2) & 63, i0 = (o4 & 3) * 4;
    const int n = bl * 128 + wv * 16 + (L & 15);
    const int k = kt * 64 + (L >> 4) * 16 + i0;
    const float inv = 127.0f / rowmax[n];
    unsigned dw = 0;
#pragma unroll
    for (int j = 0; j < 4; ++j) {
        float q = rintf(W[n * NRES + k + j] * inv);
        q = fminf(fmaxf(q, -127.f), 127.f);
        dw |= ((unsigned)((int)q & 0xff)) << (8 * j);
    }
    dst[o4] = dw;
}

// W_clf -> int8 fragment tile (16 cols, cls>=10 zero): 4096 dwords
__global__ __launch_bounds__(256) void quant_clf(const float* __restrict__ W,
                                                 const unsigned* __restrict__ slot,
                                                 unsigned* __restrict__ dst) {
    const int o4 = blockIdx.x * 256 + threadIdx.x;
    const int kt = (o4 >> 8) & 15, L = (o4 >> 2) & 63, i0 = (o4 & 3) * 4;
    const int cls = L & 15;
    const int k = kt * 64 + (L >> 4) * 16 + i0;
    const float inv = 127.0f / __uint_as_float(*slot);
    unsigned dw = 0;
    if (cls < NCLS) {
#pragma unroll
        for (int j = 0; j < 4; ++j) {
            float q = rintf(W[cls * NRES + k + j] * inv);
            q = fminf(fmaxf(q, -127.f), 127.f);
            dw |= ((unsigned)((int)q & 0xff)) << (8 * j);
        }
    }
    dst[o4] = dw;
}

__device__ __forceinline__ unsigned short f2bf(float f) {
    unsigned u = __float_as_uint(f);
    return (unsigned short)((u + 0x7fffu + ((u >> 16) & 1u)) >> 16);
}

// 16 spike bits -> 16 int8 {0,1} bytes (carry-free nibble spread:
// x*0x00204081 places bits at 0/8/16/24; shifts never overlap for x<16)
__device__ __forceinline__ v4i expand16(unsigned m16) {
    unsigned w[4];
#pragma unroll
    for (int d = 0; d < 4; ++d)
        w[d] = (((m16 >> (4 * d)) & 15u) * 0x00204081u) & 0x01010101u;
    return *(v4i*)&w[0];
}

// LDS-only barrier: full block rendezvous + LDS ordering (lgkmcnt), WITHOUT
// the vmcnt(0) drain __syncthreads emits. Used ONLY at S3, where the sole
// outstanding VMEM is the agent-scope publish store — whose fabric ACK has no
// in-block ordering requirement (remote consumer, self-validating monotone
// tags). Rendezvous/pacing is preserved (this is NOT R5's barrier removal).
__device__ __forceinline__ void bar_lds() {
    asm volatile("s_waitcnt lgkmcnt(0)" ::: "memory");
    __builtin_amdgcn_sched_barrier(0);
    __builtin_amdgcn_s_barrier();
    __builtin_amdgcn_sched_barrier(0);
    asm volatile("" ::: "memory");
}

// ---------------------------------------------------------------------------
// 256 blocks x 512 threads (1/CU). Block = (group g, slot bl): 16 batch rows
// x 128 neurons, int8 W slice LDS-resident. Producer-major tagged-mask
// transport (verified 3.48 ms kernel). SINGLE isolated change vs that kernel:
// in-loop S3 is an LDS-only barrier (bar_lds) instead of __syncthreads —
// removes the per-step wait for the publish store's coherence-point ACK
// (~300-900 cy) from the critical path. S2 stays __syncthreads (its drain is
// ~free: all loads already consumed). All LDS hazards still ordered: A/xA
// reads (pre-S3) vs next-step writes (post-S3), redC write (pre-S3) vs
// wave-0 read (post-S3). Numerics bit-identical (absmax must be exactly 32).
// ---------------------------------------------------------------------------
__global__ __launch_bounds__(512, 1) void reservoir_mfma(
    const float* __restrict__ x, const float* __restrict__ W_in,
    unsigned char* __restrict__ ws, float* __restrict__ out)
{
    // XCD co-location: 8 blocks of a group share q%8 (dispatch heuristic).
    const int q   = (int)blockIdx.x;
    const int g   = (q & 7) * 4 + ((q >> 3) & 3);
    const int bl  = q >> 5;
    const int tid = (int)threadIdx.x;
    const int L    = tid & 63;
    const int wv   = tid >> 6;     // 0..7
    const int col  = L & 15;       // MFMA n-col (neuron/cls)
    const int rowq = L >> 4;       // batch quad

    extern __shared__ char lds[];
    char* B_lds = lds;                                   // 131072 B
    char* A_lds = lds + 131072;                          // 16 x 1040 B
    unsigned short* xA = (unsigned short*)(lds + 131072 + 16 * 1040);  // 16x32 bf16
    char* redC = lds + 131072 + 16 * 1040 + 1024;        // 8 KB clf partials

    const float* rowmax = (const float*)(ws + ROWMAX_OFF);
    const float cscale = __uint_as_float(*(const unsigned*)(ws + SLOTC_OFF)) * (1.0f / 127.0f);
    unsigned char* maskbuf = ws + MASK_OFF;
    const unsigned char* wqf = ws + WQF_OFF;
    const unsigned char* wcf = ws + WCF_OFF;

    const int nn = bl * 128 + wv * 16 + col;             // my output neuron
    const float dscale = rowmax[nn] * (1.0f / 127.0f);
    const bool clfBlk = (bl == 0);

    // ---- load my 128 KB weight slice into LDS
    {
        const v4i* src = (const v4i*)(wqf + (size_t)bl * 131072);
        v4i* dst = (v4i*)B_lds;
        for (int i = tid; i < 8192; i += 512) dst[i] = src[i];
    }

    // ---- W_in hi/lo bf16 B-fragments
    v8s binf_h, binf_l;
#pragma unroll
    for (int i = 0; i < 8; ++i) {
        const int c = (rowq * 8 + i) & 15;
        const float w = W_in[nn * CIN + c];
        const unsigned short h = f2bf(w);
        const float wl = w - __uint_as_float((unsigned)h << 16);
        binf_h[i] = (short)h;
        binf_l[i] = (short)f2bf(wl);
    }

    // ---- classifier fragments preloaded to registers (block 0: wave wv owns kt=2wv,2wv+1)
    v4i bcf0 = {0,0,0,0}, bcf1 = {0,0,0,0};
    if (clfBlk) {
        bcf0 = *(const v4i*)(wcf + (2 * wv + 0) * 1024 + L * 16);
        bcf1 = *(const v4i*)(wcf + (2 * wv + 1) * 1024 + L * 16);
    }

    float v[4]  = {0.f, 0.f, 0.f, 0.f};
    int   accv[4] = {0, 0, 0, 0};
    float vc[4] = {0.f, 0.f, 0.f, 0.f};   // live on block0/wave0
    int   accc[4] = {0, 0, 0, 0};

    // mask poll (producer-major): thread tt polls producer P=tt>>3, rows 2k/2k+1
    const int pP = tid >> 3, pk = tid & 7;
    const unsigned long long* mybase0 = (const unsigned long long*)(maskbuf +
        (size_t)(0 * NGROUP + g) * 4096 + pP * 64 + pk * 8);
    const unsigned long long* mybase1 = (const unsigned long long*)(maskbuf +
        (size_t)(1 * NGROUP + g) * 4096 + pP * 64 + pk * 8);

    __syncthreads();

    for (int t = 0; t < TSTEPS; ++t) {
        // x_t load issued before the poll
        float xval = 0.f;
        if (tid < 256) {
            const int b = tid >> 4, c = tid & 15;
            xval = x[((size_t)(g * 16 + b) * CIN + c) * TSTEPS + t];
        }

        if (t > 0) {
            // ---- poll tagged masks of step t-1 (parity (t-1)&1), expand to A
            const unsigned long long* mp = ((t - 1) & 1) ? mybase1 : mybase0;
            const unsigned want = (unsigned)t;
            unsigned lo, hi;
            for (;;) {
                const unsigned long long u =
                    __hip_atomic_load(mp, __ATOMIC_RELAXED, __HIP_MEMORY_SCOPE_AGENT);
                lo = (unsigned)u; hi = (unsigned)(u >> 32);
                if (((lo >> 16) == want) & ((hi >> 16) == want)) break;
                __builtin_amdgcn_s_sleep(1);
            }
            // rows 2k (lo) and 2k+1 (hi) of producer P -> A[row][16P..16P+15]
            *(v4i*)(A_lds + (2 * pk + 0) * 1040 + pP * 16) = expand16(lo & 0xffffu);
            *(v4i*)(A_lds + (2 * pk + 1) * 1040 + pP * 16) = expand16(hi & 0xffffu);
        }
        // ---- stage x_t hi/lo
        if (tid < 256) {
            const int b = tid >> 4, c = tid & 15;
            const unsigned short h = f2bf(xval);
            const float lo2 = xval - __uint_as_float((unsigned)h << 16);
            xA[b * 32 + c] = h;
            xA[b * 32 + 16 + c] = f2bf(lo2);
        }
        __syncthreads();   // S2: A + xA ready (drain ~free: loads consumed)

        // ---- input projection: (xh+xl).(Wh+Wl), 2 chained bf16 MFMAs
        v4f Din;
        {
            const v8s xa = *(const v8s*)((const char*)xA + col * 64 + rowq * 16);
            v4f z = {0.f, 0.f, 0.f, 0.f};
            const v4f D1 = __builtin_amdgcn_mfma_f32_16x16x32_bf16(xa, binf_h, z, 0, 0, 0);
            Din = __builtin_amdgcn_mfma_f32_16x16x32_bf16(xa, binf_l, D1, 0, 0, 0);
        }

        // ---- recurrent: 16 x mfma_i32_16x16x64_i8, 2 independent chains (exact)
        v4i Drec = {0, 0, 0, 0};
        if (t > 0) {
            const char* Bb = B_lds + wv * 16384;
            const char* Ab = A_lds + col * 1040 + rowq * 16;
            v4i Dr0 = {0,0,0,0}, Dr1 = {0,0,0,0};
#pragma unroll 4
            for (int kt = 0; kt < 16; kt += 2) {
                const v4i a0 = *(const v4i*)(Ab + kt * 64);
                const v4i b0 = *(const v4i*)(Bb + kt * 1024 + L * 16);
                const v4i a1 = *(const v4i*)(Ab + (kt + 1) * 64);
                const v4i b1 = *(const v4i*)(Bb + (kt + 1) * 1024 + L * 16);
                Dr0 = __builtin_amdgcn_mfma_i32_16x16x64_i8(a0, b0, Dr0, 0, 0, 0);
                Dr1 = __builtin_amdgcn_mfma_i32_16x16x64_i8(a1, b1, Dr1, 0, 0, 0);
            }
#pragma unroll
            for (int r = 0; r < 4; ++r) Drec[r] = Dr0[r] + Dr1[r];
        }

        // ---- LIF + spikes + ballots
        unsigned long long bal0, bal1, bal2, bal3;
        {
            float vn; int s;
            vn = ALPHA * v[0] + Din[0] + dscale * (float)Drec[0];
            s = (vn >= THRESH); accv[0] += s; v[0] = s ? 0.f : vn; bal0 = __ballot(s);
            vn = ALPHA * v[1] + Din[1] + dscale * (float)Drec[1];
            s = (vn >= THRESH); accv[1] += s; v[1] = s ? 0.f : vn; bal1 = __ballot(s);
            vn = ALPHA * v[2] + Din[2] + dscale * (float)Drec[2];
            s = (vn >= THRESH); accv[2] += s; v[2] = s ? 0.f : vn; bal2 = __ballot(s);
            vn = ALPHA * v[3] + Din[3] + dscale * (float)Drec[3];
            s = (vn >= THRESH); accv[3] += s; v[3] = s ? 0.f : vn; bal3 = __ballot(s);
        }

        // ---- publish tagged masks (tag = t+1): lanes 0..15 write ONE
        //      contiguous 64B line at producer slot P=bl*8+wv
        {
            const int p = t & 1;
            if (L < 16) {
                const int b = L;
                const unsigned long long bb = (b & 2) ? ((b & 1) ? bal3 : bal2)
                                                      : ((b & 1) ? bal1 : bal0);
                const unsigned fld = (unsigned)((bb >> ((b >> 2) * 16)) & 0xFFFFu);
                unsigned* mp = (unsigned*)(maskbuf +
                    (size_t)(p * NGROUP + g) * 4096 + (bl * 8 + wv) * 64 + b * 4);
                __hip_atomic_store(mp, ((unsigned)(t + 1) << 16) | fld,
                                   __ATOMIC_RELAXED, __HIP_MEMORY_SCOPE_AGENT);
            }
        }

        // ---- classifier partials (block 0, spread: wave wv does kt=2wv,2wv+1)
        if (clfBlk && t > 0) {
            const char* Ab = A_lds + col * 1040 + rowq * 16;
            v4i Dc = {0, 0, 0, 0};
            const v4i a0 = *(const v4i*)(Ab + (2 * wv + 0) * 64);
            const v4i a1 = *(const v4i*)(Ab + (2 * wv + 1) * 64);
            Dc = __builtin_amdgcn_mfma_i32_16x16x64_i8(a0, bcf0, Dc, 0, 0, 0);
            Dc = __builtin_amdgcn_mfma_i32_16x16x64_i8(a1, bcf1, Dc, 0, 0, 0);
            *(v4i*)(redC + wv * 1024 + L * 16) = Dc;
        }
        bar_lds();   // S3: rendezvous + LDS ordering; publish ACK NOT drained

        // ---- classifier reduce + LIF (block 0, wave 0; reads redC after S3)
        if (clfBlk && wv == 0 && t > 0) {
            v4i c0 = *(const v4i*)(redC + 0 * 1024 + L * 16);
#pragma unroll
            for (int jj = 1; jj < 8; ++jj) {
                const v4i cj = *(const v4i*)(redC + jj * 1024 + L * 16);
#pragma unroll
                for (int r = 0; r < 4; ++r) c0[r] += cj[r];
            }
#pragma unroll
            for (int r = 0; r < 4; ++r) {
                const float vcn = ALPHA * vc[r] + cscale * (float)c0[r];
                const int sc = (vcn >= THRESH);
                accc[r] += sc;
                vc[r] = sc ? 0.f : vcn;
            }
        }
        // no end-of-loop barrier: S3 separates this step's A/xA reads from the
        // next step's poll-gated A/xA writes.
    }

    // ---- epilogue: classifier flush with s_{T-1} (parity 1, tag TSTEPS)
    if (clfBlk) {
        {
            const unsigned want = (unsigned)TSTEPS;
            unsigned lo, hi;
            for (;;) {
                const unsigned long long u =
                    __hip_atomic_load(mybase1, __ATOMIC_RELAXED, __HIP_MEMORY_SCOPE_AGENT);
                lo = (unsigned)u; hi = (unsigned)(u >> 32);
                if (((lo >> 16) == want) & ((hi >> 16) == want)) break;
                __builtin_amdgcn_s_sleep(1);
            }
            *(v4i*)(A_lds + (2 * pk + 0) * 1040 + pP * 16) = expand16(lo & 0xffffu);
            *(v4i*)(A_lds + (2 * pk + 1) * 1040 + pP * 16) = expand16(hi & 0xffffu);
        }
        __syncthreads();
        {
            const char* Ab = A_lds + col * 1040 + rowq * 16;
            v4i Dc = {0, 0, 0, 0};
            const v4i a0 = *(const v4i*)(Ab + (2 * wv + 0) * 64);
            const v4i a1 = *(const v4i*)(Ab + (2 * wv + 1) * 64);
            Dc = __builtin_amdgcn_mfma_i32_16x16x64_i8(a0, bcf0, Dc, 0, 0, 0);
            Dc = __builtin_amdgcn_mfma_i32_16x16x64_i8(a1, bcf1, Dc, 0, 0, 0);
            *(v4i*)(redC + wv * 1024 + L * 16) = Dc;
        }
        __syncthreads();
        if (wv == 0 && col < NCLS) {
            v4i c0 = *(const v4i*)(redC + 0 * 1024 + L * 16);
#pragma unroll
            for (int jj = 1; jj < 8; ++jj) {
                const v4i cj = *(const v4i*)(redC + jj * 1024 + L * 16);
#pragma unroll
                for (int r = 0; r < 4; ++r) c0[r] += cj[r];
            }
#pragma unroll
            for (int r = 0; r < 4; ++r) {
                const float vcn = ALPHA * vc[r] + cscale * (float)c0[r];
                const int sc = (vcn >= THRESH);
                out[(size_t)(g * 16 + rowq * 4 + r) * NCLS + col] = (float)(accc[r] + sc);
            }
        }
    }
    {
#pragma unroll
        for (int r = 0; r < 4; ++r) {
            const int bglob = g * 16 + rowq * 4 + r;
            out[BATCH * NCLS + (size_t)bglob * NRES + nn] = (float)accv[r];
        }
    }
}

extern "C" void kernel_launch(void* const* d_in, const int* in_sizes, int n_in,
                              void* d_out, int out_size, void* d_ws, size_t ws_size,
                              hipStream_t stream) {
    (void)in_sizes; (void)n_in; (void)out_size; (void)ws_size;
    const float* x     = (const float*)d_in[0];
    const float* W_in  = (const float*)d_in[1];
    const float* W_res = (const float*)d_in[2];
    const float* W_clf = (const float*)d_in[3];
    float* out = (float*)d_out;
    unsigned char* ws = (unsigned char*)d_ws;

    // zero: scale slots + rowmax + ENTIRE tagged-mask region (tags 0 never match)
    hipMemsetAsync(ws, 0, MASK_OFF + 262144, stream);
    rowmax_kernel<<<256, 256, 0, stream>>>(W_res, (float*)(ws + ROWMAX_OFF));
    maxabs_kernel<<<16, 256, 0, stream>>>(W_clf, NCLS * NRES, (unsigned*)(ws + SLOTC_OFF));
    quant_res<<<1024, 256, 0, stream>>>(W_res, (const float*)(ws + ROWMAX_OFF),
                                        (unsigned*)(ws + WQF_OFF));
    quant_clf<<<16, 256, 0, stream>>>(W_clf, (const unsigned*)(ws + SLOTC_OFF),
                                      (unsigned*)(ws + WCF_OFF));
    reservoir_mfma<<<NGROUP * BPG, 512, LDS_BYTES, stream>>>(x, W_in, ws, out);
}